// Round 2
// baseline (369.075 us; speedup 1.0000x reference)
//
#include <hip/hip_runtime.h>

#define VQ_D 64
#define VQ_K 512

// ---------------------------------------------------------------------------
// numpy pairwise_sum replication for n=64 (<= PW_BLOCKSIZE=128):
// 8 accumulators r[j] = x[j] + x[j+8] + ... + x[j+56] (sequential), then
// ((r0+r1)+(r2+r3)) + ((r4+r5)+(r6+r7)). Squares are rounded to f32 BEFORE
// summing (np.sum(x**2) sums a rounded temp array). __f*_rn intrinsics
// forbid fma contraction so every rounding matches numpy.
// ---------------------------------------------------------------------------
__device__ __forceinline__ float np_sumsq64(const float* __restrict__ x)
{
    float r[8];
#pragma unroll
    for (int j = 0; j < 8; ++j) r[j] = __fmul_rn(x[j], x[j]);
#pragma unroll
    for (int i = 8; i < 64; i += 8) {
#pragma unroll
        for (int j = 0; j < 8; ++j)
            r[j] = __fadd_rn(r[j], __fmul_rn(x[i + j], x[i + j]));
    }
    return __fadd_rn(
        __fadd_rn(__fadd_rn(r[0], r[1]), __fadd_rn(r[2], r[3])),
        __fadd_rn(__fadd_rn(r[4], r[5]), __fadd_rn(r[6], r[7])));
}

// ---------------------------------------------------------------------------
// Pass A: bit-exact replication of the numpy f32 reference:
//   dist[r,k] = fl( fl( s1[r] - fl(2*M[r,k]) ) + s2[k] )
//   M[r,k] = sequential-FMA dot (BLAS sgemm micro-kernel k-order),
//   argmin = first minimum (strict <, ascending k).
// Plus z_q = fl(z + fl(e - z)) (STE rounding) and f64 loss partials over
// f32-rounded squared diffs.
// ---------------------------------------------------------------------------
__global__ __launch_bounds__(256) void vq_main_kernel(
    const float* __restrict__ z,
    const float* __restrict__ emb,
    float* __restrict__ zq_out,
    float* __restrict__ idx_out,
    double* __restrict__ partials,
    int rows, int use_atomic)
{
    __shared__ float s2[VQ_K];
    __shared__ double wsum[4];

    for (int k = threadIdx.x; k < VQ_K; k += 256)
        s2[k] = np_sumsq64(emb + (size_t)k * VQ_D);
    __syncthreads();

    const int row = blockIdx.x * 256 + threadIdx.x;
    double lsum = 0.0;

    if (row < rows) {
        float zr[VQ_D];
        const float* zp = z + (size_t)row * VQ_D;
#pragma unroll
        for (int d = 0; d < VQ_D; d += 4) {
            const float4 v = *reinterpret_cast<const float4*>(zp + d);
            zr[d] = v.x; zr[d + 1] = v.y; zr[d + 2] = v.z; zr[d + 3] = v.w;
        }

        const float s1 = np_sumsq64(zr);

        float best = 3.4e38f;
        int bi = 0;
        for (int k = 0; k < VQ_K; k += 4) {
            // Wave-uniform code addresses -> scalar loads; 4 independent
            // sequential-FMA chains give ILP without changing per-code order.
            const float* e0 = emb + (size_t)(k + 0) * VQ_D;
            const float* e1 = emb + (size_t)(k + 1) * VQ_D;
            const float* e2 = emb + (size_t)(k + 2) * VQ_D;
            const float* e3 = emb + (size_t)(k + 3) * VQ_D;
            float a0 = 0.f, a1 = 0.f, a2 = 0.f, a3 = 0.f;
#pragma unroll
            for (int d = 0; d < VQ_D; ++d) {
                const float zd = zr[d];
                a0 = fmaf(zd, e0[d], a0);
                a1 = fmaf(zd, e1[d], a1);
                a2 = fmaf(zd, e2[d], a2);
                a3 = fmaf(zd, e3[d], a3);
            }
            float t;
            t = __fadd_rn(__fsub_rn(s1, __fmul_rn(2.0f, a0)), s2[k + 0]);
            if (t < best) { best = t; bi = k + 0; }
            t = __fadd_rn(__fsub_rn(s1, __fmul_rn(2.0f, a1)), s2[k + 1]);
            if (t < best) { best = t; bi = k + 1; }
            t = __fadd_rn(__fsub_rn(s1, __fmul_rn(2.0f, a2)), s2[k + 2]);
            if (t < best) { best = t; bi = k + 2; }
            t = __fadd_rn(__fsub_rn(s1, __fmul_rn(2.0f, a3)), s2[k + 3]);
            if (t < best) { best = t; bi = k + 3; }
        }

        const float* eb = emb + (size_t)bi * VQ_D;
        float* zq = zq_out + (size_t)row * VQ_D;
#pragma unroll
        for (int d = 0; d < VQ_D; d += 4) {
            float4 ev, ov;
            ev.x = eb[d]; ev.y = eb[d + 1]; ev.z = eb[d + 2]; ev.w = eb[d + 3];
            const float d0 = __fsub_rn(ev.x, zr[d]);
            const float d1 = __fsub_rn(ev.y, zr[d + 1]);
            const float d2 = __fsub_rn(ev.z, zr[d + 2]);
            const float d3 = __fsub_rn(ev.w, zr[d + 3]);
            ov.x = __fadd_rn(zr[d],     d0);
            ov.y = __fadd_rn(zr[d + 1], d1);
            ov.z = __fadd_rn(zr[d + 2], d2);
            ov.w = __fadd_rn(zr[d + 3], d3);
            *reinterpret_cast<float4*>(zq + d) = ov;
            lsum += (double)__fmul_rn(d0, d0) + (double)__fmul_rn(d1, d1)
                  + (double)__fmul_rn(d2, d2) + (double)__fmul_rn(d3, d3);
        }
        idx_out[row] = (float)bi;
    }

    // Deterministic block reduction of the f64 loss partial.
#pragma unroll
    for (int off = 32; off > 0; off >>= 1)
        lsum += __shfl_down(lsum, off, 64);
    const int lane = threadIdx.x & 63, wid = threadIdx.x >> 6;
    if (lane == 0) wsum[wid] = lsum;
    __syncthreads();
    if (threadIdx.x == 0) {
        const double bs = wsum[0] + wsum[1] + wsum[2] + wsum[3];
        if (use_atomic) atomicAdd(partials, bs);
        else partials[blockIdx.x] = bs;
    }
}

// ---------------------------------------------------------------------------
// Pass B: deterministic reduce of per-block partials; write scalar loss.
// loss = (1 + BETA) * sum((z_q - z)^2) / N   with BETA = 0.25.
// ---------------------------------------------------------------------------
__global__ __launch_bounds__(256) void vq_finalize_kernel(
    const double* __restrict__ partials, int nparts,
    float* __restrict__ loss_out, double inv_n)
{
    __shared__ double wsum[4];
    double s = 0.0;
    for (int i = threadIdx.x; i < nparts; i += 256) s += partials[i];
#pragma unroll
    for (int off = 32; off > 0; off >>= 1)
        s += __shfl_down(s, off, 64);
    const int lane = threadIdx.x & 63, wid = threadIdx.x >> 6;
    if (lane == 0) wsum[wid] = s;
    __syncthreads();
    if (threadIdx.x == 0)
        loss_out[0] = (float)(1.25 * (wsum[0] + wsum[1] + wsum[2] + wsum[3]) * inv_n);
}

extern "C" void kernel_launch(void* const* d_in, const int* in_sizes, int n_in,
                              void* d_out, int out_size, void* d_ws, size_t ws_size,
                              hipStream_t stream) {
    const float* z   = (const float*)d_in[0];
    const float* emb = (const float*)d_in[1];
    float* out = (float*)d_out;

    const int zn   = in_sizes[0];      // 64*4096*64 = 16777216
    const int rows = zn / VQ_D;        // 262144

    // Output layout (f32 buffer, tuple flattened in return order):
    // [0, zn) z_q | [zn] loss | [zn+1, zn+1+rows) indices (as floats)
    float* zq_out   = out;
    float* loss_out = out + zn;
    float* idx_out  = out + zn + 1;

    const int grid = (rows + 255) / 256;   // 1024 blocks
    double* partials = (double*)d_ws;
    const int use_atomic = (ws_size < (size_t)grid * sizeof(double)) ? 1 : 0;
    if (use_atomic) {
        hipMemsetAsync(d_ws, 0, sizeof(double), stream);
    }

    vq_main_kernel<<<grid, 256, 0, stream>>>(z, emb, zq_out, idx_out,
                                             partials, rows, use_atomic);
    vq_finalize_kernel<<<1, 256, 0, stream>>>(partials, use_atomic ? 1 : grid,
                                              loss_out, 1.0 / (double)zn);
}